// Round 1
// baseline (699.807 us; speedup 1.0000x reference)
//
#include <hip/hip_runtime.h>
#include <math.h>

// RealNVP, 8 layers, B=262144, H=128, scalar coupling input.
// Level-1 factorization: h2_pre[b,i] = x*S1[k,i]+S0[k,i], k = #{t_j < x}.
// Level-2 (new): within bin k every folded unit is LINEAR -> st(x) is PWL with
// <=128 sub-breakpoints per bin. Precompute sorted crossings U[k][*] and
// cumulative (Ax,Bx,Ay,By) segment coeffs C[k][*]; per sample: 2-round search
// + one float4 load + 2 fma.

#define BN_ 262144
#define H_ 128
#define NBINS 129

// ws layout (float offsets)
#define OFF_ST  (3*BN_)                        // 4 floats: stats[par]={sum,sumsq}
#define OFF_BIN (3*BN_+8)                      // 512: cnt[0..131], sx[132..263], sxx[264..395]
#define OFF_T   (3*BN_+520)                    // 128: breakpoints (unsorted)
#define OFF_S   (3*BN_+648)                    // float2 ST[NBINS][H_] (col k, unit i)
#define OFF_BB  (3*BN_+648+2*128*132)          // uchar[B]: per-sample bin
#define OFF_TS  (OFF_BB + BN_/4)               // 128: sorted breakpoints
#define OFF_UP  (OFF_TS + 128)                 // float Upiv[NBINS][8]
#define OFF_U   (OFF_UP + NBINS*8)             // float U[NBINS][H_] (sorted, INF pad)
#define OFF_C   (OFF_U + NBINS*H_)             // float4 C[NBINS][132]

__global__ void k_zero(float* ws) {
    if (threadIdx.x < 4) ws[OFF_ST + threadIdx.x] = 0.f;
}

__global__ __launch_bounds__(1024) void k_init(const float* __restrict__ x,
                                               float* __restrict__ ws) {
    int b = blockIdx.x * 1024 + threadIdx.x;
    float2 xv = ((const float2*)x)[b];
    ws[b] = xv.x;
    ws[BN_ + b] = xv.y;
    ws[2*BN_ + b] = 0.f;
    float s = xv.y, ss = xv.y * xv.y;
    for (int off = 32; off; off >>= 1) {
        s += __shfl_down(s, off);
        ss += __shfl_down(ss, off);
    }
    __shared__ float rs[16], rss[16];
    int lane = threadIdx.x & 63, wid = threadIdx.x >> 6;
    if (lane == 0) { rs[wid] = s; rss[wid] = ss; }
    __syncthreads();
    if (threadIdx.x == 0) {
        float a = 0.f, c = 0.f;
        for (int w = 0; w < 16; w++) { a += rs[w]; c += rss[w]; }
        atomicAdd(&ws[OFF_ST + 0], a);
        atomicAdd(&ws[OFF_ST + 1], c);
    }
}

__device__ __forceinline__ float bred128(float v, volatile float* tmp, int tid) {
    for (int off = 32; off; off >>= 1) v += __shfl_down(v, off);
    if ((tid & 63) == 0) tmp[tid >> 6] = v;
    __syncthreads();
    float r = tmp[0] + tmp[1];
    __syncthreads();
    return r;
}

// 128 blocks x 128 threads: block i builds S-table column set for unit i
// (all 129 intervals), written TRANSPOSED: ST[k][i]. Block 0 also writes
// unsorted + sorted breakpoints, zeroes bins and next stats slot.
__global__ __launch_bounds__(128) void k_prep(
    const float* __restrict__ v1, const float* __restrict__ g1,
    const float* __restrict__ bn1g, const float* __restrict__ bn1b,
    const float* __restrict__ v2, const float* __restrict__ g2,
    const float* __restrict__ b2,
    float* __restrict__ ws, int l, int par) {
    const int j = threadIdx.x, i = blockIdx.x;
    __shared__ float sA[H_], sC[H_], sT[H_], vrow[H_];
    __shared__ int order[H_];
    __shared__ float2 scan2[H_];
    __shared__ float red[2];

    float Ssum = ws[OFF_ST + 2*par], SSq = ws[OFF_ST + 2*par + 1];
    float mx = Ssum * (1.f / BN_);
    float vx = fmaxf(SSq * (1.f / BN_) - mx * mx, 0.f);

    float g1v = g1[l*H_ + j];
    float w1 = (v1[l*H_ + j] >= 0.f) ? g1v : -g1v;
    float r = rsqrtf(vx * g1v * g1v + 1e-5f);
    float a = w1 * r * bn1g[l*H_ + j];
    float c = bn1b[l*H_ + j] - mx * a;
    float tj = (a != 0.f) ? (-c / a) : 3.0e38f;
    sA[j] = a; sC[j] = c; sT[j] = tj;
    __syncthreads();

    int rk = 0;
    for (int q = 0; q < H_; q++) {
        float tq = sT[q];
        rk += ((tq < tj) || (tq == tj && q < j)) ? 1 : 0;
    }
    order[rk] = j;

    float vv = v2[l*H_*H_ + i*H_ + j];
    vrow[j] = vv;
    float n2 = bred128(vv * vv, red, j);
    float wsc = g2[l*H_ + i] / sqrtf(n2);
    float w = wsc * vv;
    bool bm = (a < 0.f) || (a == 0.f && c > 0.f);
    float base1 = bred128(bm ? w * a : 0.f, red, j);
    float base0 = bred128(bm ? w * c : 0.f, red, j);

    int jj = order[j];
    float aa = sA[jj], cc = sC[jj], vj = vrow[jj];
    float d1 = 0.f, d0 = 0.f;
    if (aa != 0.f) {
        float sg = (aa > 0.f) ? 1.f : -1.f;
        float wj = wsc * vj;
        d1 = sg * wj * aa; d0 = sg * wj * cc;
    }
    scan2[j] = make_float2(d1, d0);
    __syncthreads();
    for (int off = 1; off < H_; off <<= 1) {
        float2 add = (j >= off) ? scan2[j - off] : make_float2(0.f, 0.f);
        __syncthreads();
        scan2[j].x += add.x; scan2[j].y += add.y;
        __syncthreads();
    }
    float b2i = b2[l*H_ + i];
    float2* ST = (float2*)(ws + OFF_S);
    float2 sj = scan2[j];
    ST[(j + 1) * H_ + i] = make_float2(base1 + sj.x, base0 + sj.y + b2i);
    if (j == 0) ST[i] = make_float2(base1, base0 + b2i);

    if (i == 0) {
        ws[OFF_T + j] = tj;
        ws[OFF_TS + rk] = tj;                 // sorted breakpoints
        float* bins = ws + OFF_BIN;
        bins[j] = 0.f; bins[j + 128] = 0.f; bins[j + 256] = 0.f; bins[j + 384] = 0.f;
        if (j < 2) ws[OFF_ST + 2*(1 - par) + j] = 0.f;
    }
}

// 256 blocks x 1024: per-sample bin + per-interval (cnt, sum x, sum x^2)
__global__ __launch_bounds__(1024) void k_hist(float* __restrict__ ws, int rev) {
    const int tid = threadIdx.x;
    const int b = blockIdx.x * 1024 + tid;
    __shared__ float lt[H_];
    __shared__ float lb[4 * 396];
    if (tid < H_) lt[tid] = ws[OFF_T + tid];
    for (int e = tid; e < 4 * 396; e += 1024) lb[e] = 0.f;
    __syncthreads();
    float x = rev ? ws[BN_ + b] : ws[b];
    int bin = 0;
    #pragma unroll 16
    for (int q = 0; q < H_; q++) bin += (lt[q] < x) ? 1 : 0;
    ((unsigned char*)(ws + OFF_BB))[b] = (unsigned char)bin;
    float* lbr = lb + ((tid >> 6) & 3) * 396;
    atomicAdd(&lbr[bin], 1.f);
    atomicAdd(&lbr[132 + bin], x);
    atomicAdd(&lbr[264 + bin], x * x);
    __syncthreads();
    float* bins = ws + OFF_BIN;
    for (int e = tid; e < 396; e += 1024) {
        float v = lb[e] + lb[396 + e] + lb[792 + e] + lb[1188 + e];
        atomicAdd(&bins[e], v);
    }
}

// NBINS blocks x 128 threads: block k = bin k. Each block redundantly computes
// exact BN2 stats from interval moments (coalesced via transposed ST), folds
// BN2 into (a,c) per unit, finds in-bin relu crossings, sorts them, and
// prefix-scans the (wf-weighted) toggles into segment coeffs C[k][s] plus the
// sorted crossing list U[k][*] (INF-padded) and 8 search pivots Upiv[k][*].
__global__ __launch_bounds__(128) void k_prep2(
    const float* __restrict__ bn2g, const float* __restrict__ bn2b,
    const float* __restrict__ wf, const float* __restrict__ bf,
    float* __restrict__ ws, int l) {
    const int j = threadIdx.x, k = blockIdx.x;
    __shared__ float skey[H_];
    __shared__ float sval[H_];
    __shared__ float4 sc4[H_];
    __shared__ float red[2];

    const float2* ST = (const float2*)(ws + OFF_S);
    const float* bins = ws + OFF_BIN;
    float pm = 0.f, pe = 0.f;
    float2 mys = make_float2(0.f, 0.f);
    for (int kk = 0; kk < NBINS; kk++) {
        float2 sv = ST[kk * H_ + j];
        float cn = bins[kk], sx = bins[132 + kk], sxx = bins[264 + kk];
        pm += sv.x * sx + sv.y * cn;
        pe += sv.x * sv.x * sxx + 2.f * sv.x * sv.y * sx + sv.y * sv.y * cn;
        if (kk == k) mys = sv;
    }
    float mean = pm * (1.f / BN_);
    float var = fmaxf(pe * (1.f / BN_) - mean * mean, 0.f);
    float R = bn2g[l*H_ + j] * rsqrtf(var + 1e-5f);
    float a = mys.x * R;
    float c = (mys.y - mean) * R + bn2b[l*H_ + j];

    float lo = (k > 0) ? ws[OFF_TS + (k - 1)] : -INFINITY;
    float hi = (k < NBINS - 1) ? ws[OFF_TS + k] : INFINITY;
    bool act;
    if (k == 0) act = (a < 0.f) || (a == 0.f && c > 0.f);
    else        act = (fmaf(a, lo, c) > 0.f);
    float u = (a != 0.f) ? (-c / a) : INFINITY;
    bool rel = (a != 0.f) && (u > lo) && (u < hi);
    float key = rel ? u : INFINITY;
    skey[j] = key;
    __syncthreads();
    int rk = 0;
    for (int q = 0; q < H_; q++) {
        float kq = skey[q];
        rk += ((kq < key) || (kq == key && q < j)) ? 1 : 0;
    }
    float w0 = wf[l*2*H_ + j], w1 = wf[l*2*H_ + H_ + j];
    float bA0 = bred128(act ? w0 * a : 0.f, red, j);
    float bB0 = bred128(act ? w0 * c : 0.f, red, j);
    float bA1 = bred128(act ? w1 * a : 0.f, red, j);
    float bB1 = bred128(act ? w1 * c : 0.f, red, j);
    float sg = rel ? ((a > 0.f) ? 1.f : -1.f) : 0.f;
    sval[rk] = key;
    sc4[rk] = make_float4(sg * w0 * a, sg * w0 * c, sg * w1 * a, sg * w1 * c);
    __syncthreads();
    for (int off = 1; off < H_; off <<= 1) {
        float4 add = (j >= off) ? sc4[j - off] : make_float4(0.f, 0.f, 0.f, 0.f);
        __syncthreads();
        sc4[j].x += add.x; sc4[j].y += add.y; sc4[j].z += add.z; sc4[j].w += add.w;
        __syncthreads();
    }
    float bfx = bf[2*l], bfy = bf[2*l + 1];
    ws[OFF_U + k * H_ + j] = sval[j];
    if (j < 8) ws[OFF_UP + k * 8 + j] = sval[16 * j + 15];
    float4* Cg = (float4*)(ws + OFF_C) + k * 132;
    float4 sj = sc4[j];
    Cg[j + 1] = make_float4(bA0 + sj.x, bB0 + bfx + sj.y, bA1 + sj.z, bB1 + bfy + sj.w);
    if (j == 0) Cg[0] = make_float4(bA0, bB0 + bfx, bA1, bB1 + bfy);
}

// 1024 blocks x 256: per-sample: sub-bin search (LDS pivots + 4xfloat4) ->
// one float4 segment coeff -> 2 fma -> tanh/exp -> coupling update.
__global__ __launch_bounds__(256) void k_step(
    float* __restrict__ ws, float* __restrict__ out,
    int rev, int last, int par) {
    __shared__ float4 lup4[NBINS * 2];
    __shared__ float rsc[8];
    const int tid = threadIdx.x;
    float* lup = (float*)lup4;
    for (int e = tid; e < NBINS * 8; e += 256) lup[e] = ws[OFF_UP + e];
    __syncthreads();

    const int b = blockIdx.x * 256 + tid;
    float x0v = ws[b], x1v = ws[BN_ + b];
    float xin = rev ? x1v : x0v;
    float xo  = rev ? x0v : x1v;
    int kb = ((const unsigned char*)(ws + OFF_BB))[b];

    float4 p0 = lup4[kb * 2], p1 = lup4[kb * 2 + 1];
    int s16 = (p0.x < xin) + (p0.y < xin) + (p0.z < xin) + (p0.w < xin)
            + (p1.x < xin) + (p1.y < xin) + (p1.z < xin) + (p1.w < xin);
    const float4* Ur = (const float4*)(ws + OFF_U + kb * H_ + s16 * 16);
    float4 q0 = Ur[0], q1 = Ur[1], q2 = Ur[2], q3 = Ur[3];
    int c2 = (q0.x < xin) + (q0.y < xin) + (q0.z < xin) + (q0.w < xin)
           + (q1.x < xin) + (q1.y < xin) + (q1.z < xin) + (q1.w < xin)
           + (q2.x < xin) + (q2.y < xin) + (q2.z < xin) + (q2.w < xin)
           + (q3.x < xin) + (q3.y < xin) + (q3.z < xin) + (q3.w < xin);
    int s = s16 * 16 + c2;
    float4 C = ((const float4*)(ws + OFF_C))[kb * 132 + s];
    float stx = fmaf(C.x, xin, C.y);
    float sty = fmaf(C.z, xin, C.w);

    float sv = tanhf(stx);
    float y = expf(sv) * xo + sty;
    float sl = ws[2*BN_ + b] + sv;

    if (!last) {
        if (rev) ws[b] = y; else ws[BN_ + b] = y;
        ws[2*BN_ + b] = sl;
        float s1 = y, s2 = y * y;
        for (int off = 32; off; off >>= 1) {
            s1 += __shfl_down(s1, off);
            s2 += __shfl_down(s2, off);
        }
        int lane = tid & 63, wid = tid >> 6;
        if (lane == 0) { rsc[wid] = s1; rsc[4 + wid] = s2; }
        __syncthreads();
        if (tid == 0) {
            float a = 0.f, c = 0.f;
            for (int w = 0; w < 4; w++) { a += rsc[w]; c += rsc[4 + w]; }
            atomicAdd(&ws[OFF_ST + 2*(1 - par)], a);
            atomicAdd(&ws[OFF_ST + 2*(1 - par) + 1], c);
        }
    } else {
        float z0 = 1.f / (1.f + expf(-x0v));
        float z1 = 1.f / (1.f + expf(-y));
        ((float2*)out)[b] = make_float2(z0, z1);
        out[2*BN_ + b] = sl + logf(z0 * (1.f - z0) + 1e-4f)
                            + logf(z1 * (1.f - z1) + 1e-4f);
    }
}

extern "C" void kernel_launch(void* const* d_in, const int* in_sizes, int n_in,
                              void* d_out, int out_size, void* d_ws, size_t ws_size,
                              hipStream_t stream) {
    const float* x    = (const float*)d_in[0];
    const float* v1   = (const float*)d_in[1];
    const float* g1   = (const float*)d_in[2];
    // d_in[3] = b1: cancels exactly inside BN1 (affine input), unused.
    const float* bn1g = (const float*)d_in[4];
    const float* bn1b = (const float*)d_in[5];
    const float* v2   = (const float*)d_in[6];
    const float* g2   = (const float*)d_in[7];
    const float* b2   = (const float*)d_in[8];
    const float* bn2g = (const float*)d_in[9];
    const float* bn2b = (const float*)d_in[10];
    const float* wf   = (const float*)d_in[11];
    const float* bf   = (const float*)d_in[12];
    float* ws  = (float*)d_ws;
    float* out = (float*)d_out;

    k_zero<<<1, 64, 0, stream>>>(ws);
    k_init<<<BN_/1024, 1024, 0, stream>>>(x, ws);
    for (int l = 0; l < 8; l++) {
        int rev = (l % 2 == 0) ? 1 : 0;
        int par = l & 1;
        int last = (l == 7) ? 1 : 0;
        k_prep<<<128, 128, 0, stream>>>(v1, g1, bn1g, bn1b, v2, g2, b2, ws, l, par);
        k_hist<<<BN_/1024, 1024, 0, stream>>>(ws, rev);
        k_prep2<<<NBINS, 128, 0, stream>>>(bn2g, bn2b, wf, bf, ws, l);
        k_step<<<BN_/256, 256, 0, stream>>>(ws, out, rev, last, par);
    }
}

// Round 2
// 591.819 us; speedup vs baseline: 1.1825x; 1.1825x over previous
//
#include <hip/hip_runtime.h>
#include <math.h>

// RealNVP, 8 layers, B=262144, H=128, scalar coupling input.
// Level-1 factorization: h2_pre[b,i] = x*S1[k,i]+S0[k,i], k = #{t_j < x}.
// Level-2: within bin k every folded unit is LINEAR -> st(x) is PWL with
// <=128 sub-breakpoints per bin. Precompute sorted crossings U[k][*] and
// cumulative (Ax,Bx,Ay,By) segment coeffs C[k][*]; per sample: 2-round search
// + one float4 load + 2 fma.
// BN2 stats: per-block partial moments accumulated in k_hist (device atomics),
// so no kernel ever runs a serial L2-latency-bound stats loop.

#define BN_ 262144
#define H_ 128
#define NBINS 129

// ws layout (float offsets)
#define OFF_ST  (3*BN_)                        // 4 floats: stats[par]={sum,sumsq}
#define OFF_BIN (3*BN_+8)                      // 256: pm[0..127], pe[0..127] (BN2 moment sums)
#define OFF_T   (3*BN_+520)                    // (unused, layout keep)
#define OFF_S   (3*BN_+648)                    // float2 ST[NBINS][H_] (bin k, unit i)
#define OFF_BB  (3*BN_+648+2*128*132)          // uchar[B]: per-sample bin
#define OFF_TS  (OFF_BB + BN_/4)               // 128: sorted breakpoints
#define OFF_UP  (OFF_TS + 128)                 // float Upiv[NBINS][8]
#define OFF_U   (OFF_UP + NBINS*8)             // float U[NBINS][H_] (sorted, INF pad)
#define OFF_C   (OFF_U + NBINS*H_)             // float4 C[NBINS][132]

__global__ void k_zero(float* ws) {
    if (threadIdx.x < 4) ws[OFF_ST + threadIdx.x] = 0.f;
}

__global__ __launch_bounds__(1024) void k_init(const float* __restrict__ x,
                                               float* __restrict__ ws) {
    int b = blockIdx.x * 1024 + threadIdx.x;
    float2 xv = ((const float2*)x)[b];
    ws[b] = xv.x;
    ws[BN_ + b] = xv.y;
    ws[2*BN_ + b] = 0.f;
    float s = xv.y, ss = xv.y * xv.y;
    for (int off = 32; off; off >>= 1) {
        s += __shfl_down(s, off);
        ss += __shfl_down(ss, off);
    }
    __shared__ float rs[16], rss[16];
    int lane = threadIdx.x & 63, wid = threadIdx.x >> 6;
    if (lane == 0) { rs[wid] = s; rss[wid] = ss; }
    __syncthreads();
    if (threadIdx.x == 0) {
        float a = 0.f, c = 0.f;
        for (int w = 0; w < 16; w++) { a += rs[w]; c += rss[w]; }
        atomicAdd(&ws[OFF_ST + 0], a);
        atomicAdd(&ws[OFF_ST + 1], c);
    }
}

__device__ __forceinline__ float bred128(float v, volatile float* tmp, int tid) {
    for (int off = 32; off; off >>= 1) v += __shfl_down(v, off);
    if ((tid & 63) == 0) tmp[tid >> 6] = v;
    __syncthreads();
    float r = tmp[0] + tmp[1];
    __syncthreads();
    return r;
}

__device__ __forceinline__ float4 bred128x4(float4 v, volatile float* tmp, int tid) {
    for (int off = 32; off; off >>= 1) {
        v.x += __shfl_down(v.x, off);
        v.y += __shfl_down(v.y, off);
        v.z += __shfl_down(v.z, off);
        v.w += __shfl_down(v.w, off);
    }
    if ((tid & 63) == 0) {
        int w = (tid >> 6) * 4;
        tmp[w] = v.x; tmp[w + 1] = v.y; tmp[w + 2] = v.z; tmp[w + 3] = v.w;
    }
    __syncthreads();
    float4 r = make_float4(tmp[0] + tmp[4], tmp[1] + tmp[5],
                           tmp[2] + tmp[6], tmp[3] + tmp[7]);
    __syncthreads();
    return r;
}

// 128 blocks x 128 threads: block i builds S-table row set for unit i
// (all 129 intervals), written ST[k][i]. Block 0 also writes sorted
// breakpoints, zeroes pm/pe and next-layer stats slot.
__global__ __launch_bounds__(128) void k_prep(
    const float* __restrict__ v1, const float* __restrict__ g1,
    const float* __restrict__ bn1g, const float* __restrict__ bn1b,
    const float* __restrict__ v2, const float* __restrict__ g2,
    const float* __restrict__ b2,
    float* __restrict__ ws, int l, int par) {
    const int j = threadIdx.x, i = blockIdx.x;
    __shared__ float sA[H_], sC[H_], sT[H_], vrow[H_];
    __shared__ int order[H_];
    __shared__ float2 scan2[H_];
    __shared__ float red[2];

    float Ssum = ws[OFF_ST + 2*par], SSq = ws[OFF_ST + 2*par + 1];
    float mx = Ssum * (1.f / BN_);
    float vx = fmaxf(SSq * (1.f / BN_) - mx * mx, 0.f);

    float g1v = g1[l*H_ + j];
    float w1 = (v1[l*H_ + j] >= 0.f) ? g1v : -g1v;
    float r = rsqrtf(vx * g1v * g1v + 1e-5f);
    float a = w1 * r * bn1g[l*H_ + j];
    float c = bn1b[l*H_ + j] - mx * a;
    float tj = (a != 0.f) ? (-c / a) : 3.0e38f;
    sA[j] = a; sC[j] = c; sT[j] = tj;
    __syncthreads();

    int rk = 0;
    for (int q = 0; q < H_; q++) {
        float tq = sT[q];
        rk += ((tq < tj) || (tq == tj && q < j)) ? 1 : 0;
    }
    order[rk] = j;

    float vv = v2[l*H_*H_ + i*H_ + j];
    vrow[j] = vv;
    float n2 = bred128(vv * vv, red, j);
    float wsc = g2[l*H_ + i] / sqrtf(n2);
    float w = wsc * vv;
    bool bm = (a < 0.f) || (a == 0.f && c > 0.f);
    float base1 = bred128(bm ? w * a : 0.f, red, j);
    float base0 = bred128(bm ? w * c : 0.f, red, j);

    int jj = order[j];
    float aa = sA[jj], cc = sC[jj], vj = vrow[jj];
    float d1 = 0.f, d0 = 0.f;
    if (aa != 0.f) {
        float sg = (aa > 0.f) ? 1.f : -1.f;
        float wj = wsc * vj;
        d1 = sg * wj * aa; d0 = sg * wj * cc;
    }
    scan2[j] = make_float2(d1, d0);
    __syncthreads();
    for (int off = 1; off < H_; off <<= 1) {
        float2 add = (j >= off) ? scan2[j - off] : make_float2(0.f, 0.f);
        __syncthreads();
        scan2[j].x += add.x; scan2[j].y += add.y;
        __syncthreads();
    }
    float b2i = b2[l*H_ + i];
    float2* ST = (float2*)(ws + OFF_S);
    float2 sj = scan2[j];
    ST[(j + 1) * H_ + i] = make_float2(base1 + sj.x, base0 + sj.y + b2i);
    if (j == 0) ST[i] = make_float2(base1, base0 + b2i);

    if (i == 0) {
        ws[OFF_TS + rk] = tj;                 // sorted breakpoints
        ws[OFF_BIN + j] = 0.f;                // pm
        ws[OFF_BIN + 128 + j] = 0.f;          // pe
        if (j < 2) ws[OFF_ST + 2*(1 - par) + j] = 0.f;
    }
}

// 256 blocks x 1024: per-sample bin via 7-step binary search on sorted
// breakpoints; local sub-histogram moments in LDS; then each block folds its
// OWN local moments against ST into partial BN2 sums pm_i/pe_i and
// device-atomicAdds them (fully parallel, latency hidden at 16 waves/CU).
__global__ __launch_bounds__(1024) void k_hist(float* __restrict__ ws, int rev) {
    const int tid = threadIdx.x;
    const int b = blockIdx.x * 1024 + tid;
    __shared__ float st[H_];
    __shared__ float lb[4 * 396];
    __shared__ float red1[1024];
    __shared__ float red2[1024];
    if (tid < H_) st[tid] = ws[OFF_TS + tid];
    for (int e = tid; e < 4 * 396; e += 1024) lb[e] = 0.f;
    __syncthreads();
    float x = rev ? ws[BN_ + b] : ws[b];
    int pos = 0;
    #pragma unroll
    for (int s = 64; s; s >>= 1) pos += (st[pos + s - 1] < x) ? s : 0;
    pos += (st[pos] < x) ? 1 : 0;             // exact count of {t < x} in [0,128]
    ((unsigned char*)(ws + OFF_BB))[b] = (unsigned char)pos;
    float* lbr = lb + ((tid >> 6) & 3) * 396;
    atomicAdd(&lbr[pos], 1.f);
    atomicAdd(&lbr[132 + pos], x);
    atomicAdd(&lbr[264 + pos], x * x);
    __syncthreads();
    // partial BN2 moments: thread (i = tid&127, chunk = tid>>7) covers 17 bins
    const float2* STg = (const float2*)(ws + OFF_S);
    const int i = tid & 127, cch = tid >> 7;
    int k0 = cch * 17, k1 = (k0 + 17 < NBINS) ? k0 + 17 : NBINS;
    float pm = 0.f, pe = 0.f;
    for (int k = k0; k < k1; k++) {
        float cn  = lb[k]       + lb[396 + k]  + lb[792 + k]  + lb[1188 + k];
        float sx  = lb[132 + k] + lb[528 + k]  + lb[924 + k]  + lb[1320 + k];
        float sxx = lb[264 + k] + lb[660 + k]  + lb[1056 + k] + lb[1452 + k];
        float2 s = STg[k * H_ + i];
        pm += s.x * sx + s.y * cn;
        pe += s.x * s.x * sxx + 2.f * s.x * s.y * sx + s.y * s.y * cn;
    }
    red1[tid] = pm; red2[tid] = pe;
    __syncthreads();
    if (tid < H_) {
        float m = 0.f, e2 = 0.f;
        for (int cc = 0; cc < 8; cc++) { m += red1[cc*128 + tid]; e2 += red2[cc*128 + tid]; }
        atomicAdd(&ws[OFF_BIN + tid], m);
        atomicAdd(&ws[OFF_BIN + 128 + tid], e2);
    }
}

// NBINS blocks x 128 threads: block k = bin k. Reads precomputed BN2 moments
// (2 loads), folds BN2 into (a,c) per unit, finds in-bin relu crossings,
// sorts them, prefix-scans the wf-weighted toggles into segment coeffs
// C[k][s], sorted crossing list U[k][*] (INF pad), and 8 search pivots.
__global__ __launch_bounds__(128) void k_prep2(
    const float* __restrict__ bn2g, const float* __restrict__ bn2b,
    const float* __restrict__ wf, const float* __restrict__ bf,
    float* __restrict__ ws, int l) {
    const int j = threadIdx.x, k = blockIdx.x;
    __shared__ float skey[H_];
    __shared__ float sval[H_];
    __shared__ float4 sc4[H_];
    __shared__ float red[8];

    const float2* ST = (const float2*)(ws + OFF_S);
    float mean = ws[OFF_BIN + j] * (1.f / BN_);
    float e2   = ws[OFF_BIN + 128 + j] * (1.f / BN_);
    float var = fmaxf(e2 - mean * mean, 0.f);
    float R = bn2g[l*H_ + j] * rsqrtf(var + 1e-5f);
    float2 mys = ST[k * H_ + j];
    float a = mys.x * R;
    float c = (mys.y - mean) * R + bn2b[l*H_ + j];

    float lo = (k > 0) ? ws[OFF_TS + (k - 1)] : -INFINITY;
    float hi = (k < NBINS - 1) ? ws[OFF_TS + k] : INFINITY;
    bool act;
    if (k == 0) act = (a < 0.f) || (a == 0.f && c > 0.f);
    else        act = (fmaf(a, lo, c) > 0.f);
    float u = (a != 0.f) ? (-c / a) : INFINITY;
    bool rel = (a != 0.f) && (u > lo) && (u < hi);
    float key = rel ? u : INFINITY;
    skey[j] = key;
    __syncthreads();
    int rk = 0;
    for (int q = 0; q < H_; q++) {
        float kq = skey[q];
        rk += ((kq < key) || (kq == key && q < j)) ? 1 : 0;
    }
    float w0 = wf[l*2*H_ + j], w1 = wf[l*2*H_ + H_ + j];
    float4 bb = bred128x4(act ? make_float4(w0 * a, w0 * c, w1 * a, w1 * c)
                              : make_float4(0.f, 0.f, 0.f, 0.f), red, j);
    float sg = rel ? ((a > 0.f) ? 1.f : -1.f) : 0.f;
    sval[rk] = key;
    sc4[rk] = make_float4(sg * w0 * a, sg * w0 * c, sg * w1 * a, sg * w1 * c);
    __syncthreads();
    for (int off = 1; off < H_; off <<= 1) {
        float4 add = (j >= off) ? sc4[j - off] : make_float4(0.f, 0.f, 0.f, 0.f);
        __syncthreads();
        sc4[j].x += add.x; sc4[j].y += add.y; sc4[j].z += add.z; sc4[j].w += add.w;
        __syncthreads();
    }
    float bfx = bf[2*l], bfy = bf[2*l + 1];
    ws[OFF_U + k * H_ + j] = sval[j];
    if (j < 8) ws[OFF_UP + k * 8 + j] = sval[16 * j + 15];
    float4* Cg = (float4*)(ws + OFF_C) + k * 132;
    float4 sj = sc4[j];
    Cg[j + 1] = make_float4(bb.x + sj.x, bb.y + bfx + sj.y, bb.z + sj.z, bb.w + bfy + sj.w);
    if (j == 0) Cg[0] = make_float4(bb.x, bb.y + bfx, bb.z, bb.w + bfy);
}

// 1024 blocks x 256: per-sample: sub-bin search (LDS pivots + 4xfloat4) ->
// one float4 segment coeff -> 2 fma -> tanh/exp -> coupling update.
__global__ __launch_bounds__(256) void k_step(
    float* __restrict__ ws, float* __restrict__ out,
    int rev, int last, int par) {
    __shared__ float4 lup4[NBINS * 2];
    __shared__ float rsc[8];
    const int tid = threadIdx.x;
    float* lup = (float*)lup4;
    for (int e = tid; e < NBINS * 8; e += 256) lup[e] = ws[OFF_UP + e];
    __syncthreads();

    const int b = blockIdx.x * 256 + tid;
    float x0v = ws[b], x1v = ws[BN_ + b];
    float xin = rev ? x1v : x0v;
    float xo  = rev ? x0v : x1v;
    int kb = ((const unsigned char*)(ws + OFF_BB))[b];

    float4 p0 = lup4[kb * 2], p1 = lup4[kb * 2 + 1];
    int s16 = (p0.x < xin) + (p0.y < xin) + (p0.z < xin) + (p0.w < xin)
            + (p1.x < xin) + (p1.y < xin) + (p1.z < xin) + (p1.w < xin);
    const float4* Ur = (const float4*)(ws + OFF_U + kb * H_ + s16 * 16);
    float4 q0 = Ur[0], q1 = Ur[1], q2 = Ur[2], q3 = Ur[3];
    int c2 = (q0.x < xin) + (q0.y < xin) + (q0.z < xin) + (q0.w < xin)
           + (q1.x < xin) + (q1.y < xin) + (q1.z < xin) + (q1.w < xin)
           + (q2.x < xin) + (q2.y < xin) + (q2.z < xin) + (q2.w < xin)
           + (q3.x < xin) + (q3.y < xin) + (q3.z < xin) + (q3.w < xin);
    int s = s16 * 16 + c2;
    float4 C = ((const float4*)(ws + OFF_C))[kb * 132 + s];
    float stx = fmaf(C.x, xin, C.y);
    float sty = fmaf(C.z, xin, C.w);

    float sv = tanhf(stx);
    float y = expf(sv) * xo + sty;
    float sl = ws[2*BN_ + b] + sv;

    if (!last) {
        if (rev) ws[b] = y; else ws[BN_ + b] = y;
        ws[2*BN_ + b] = sl;
        float s1 = y, s2 = y * y;
        for (int off = 32; off; off >>= 1) {
            s1 += __shfl_down(s1, off);
            s2 += __shfl_down(s2, off);
        }
        int lane = tid & 63, wid = tid >> 6;
        if (lane == 0) { rsc[wid] = s1; rsc[4 + wid] = s2; }
        __syncthreads();
        if (tid == 0) {
            float a = 0.f, c = 0.f;
            for (int w = 0; w < 4; w++) { a += rsc[w]; c += rsc[4 + w]; }
            atomicAdd(&ws[OFF_ST + 2*(1 - par)], a);
            atomicAdd(&ws[OFF_ST + 2*(1 - par) + 1], c);
        }
    } else {
        float z0 = 1.f / (1.f + expf(-x0v));
        float z1 = 1.f / (1.f + expf(-y));
        ((float2*)out)[b] = make_float2(z0, z1);
        out[2*BN_ + b] = sl + logf(z0 * (1.f - z0) + 1e-4f)
                            + logf(z1 * (1.f - z1) + 1e-4f);
    }
}

extern "C" void kernel_launch(void* const* d_in, const int* in_sizes, int n_in,
                              void* d_out, int out_size, void* d_ws, size_t ws_size,
                              hipStream_t stream) {
    const float* x    = (const float*)d_in[0];
    const float* v1   = (const float*)d_in[1];
    const float* g1   = (const float*)d_in[2];
    // d_in[3] = b1: cancels exactly inside BN1 (affine input), unused.
    const float* bn1g = (const float*)d_in[4];
    const float* bn1b = (const float*)d_in[5];
    const float* v2   = (const float*)d_in[6];
    const float* g2   = (const float*)d_in[7];
    const float* b2   = (const float*)d_in[8];
    const float* bn2g = (const float*)d_in[9];
    const float* bn2b = (const float*)d_in[10];
    const float* wf   = (const float*)d_in[11];
    const float* bf   = (const float*)d_in[12];
    float* ws  = (float*)d_ws;
    float* out = (float*)d_out;

    k_zero<<<1, 64, 0, stream>>>(ws);
    k_init<<<BN_/1024, 1024, 0, stream>>>(x, ws);
    for (int l = 0; l < 8; l++) {
        int rev = (l % 2 == 0) ? 1 : 0;
        int par = l & 1;
        int last = (l == 7) ? 1 : 0;
        k_prep<<<128, 128, 0, stream>>>(v1, g1, bn1g, bn1b, v2, g2, b2, ws, l, par);
        k_hist<<<BN_/1024, 1024, 0, stream>>>(ws, rev);
        k_prep2<<<NBINS, 128, 0, stream>>>(bn2g, bn2b, wf, bf, ws, l);
        k_step<<<BN_/256, 256, 0, stream>>>(ws, out, rev, last, par);
    }
}